// Round 8
// baseline (232.912 us; speedup 1.0000x reference)
//
#include <hip/hip_runtime.h>
#include <hip/hip_bf16.h>

#define NEG_SLOPE 0.2f
#define LOG2E 1.4426950408889634f
#define EPB   8192   // edges per scatter block (round-0 verified; 4096 regressed)
#define BINSZ 32     // dsts per bin (256-thread blocks -> 8 blocks/CU residency)
#define CAP   2048   // arena slots per 32-dst bin (mean 1024, sigma 32 -> 32 sigma)
#define MAXC  2048   // max bins; ceil(50000/32) = 1563

#if defined(__has_builtin) && __has_builtin(__builtin_amdgcn_exp2f)
#define EXP2F(x) __builtin_amdgcn_exp2f(x)
#else
#define EXP2F(x) exp2f(x)
#endif

typedef __attribute__((ext_vector_type(8))) short bf16x8;
typedef __attribute__((ext_vector_type(4))) float f32x4;

__device__ __forceinline__ float b2f_lo(unsigned u) { return __uint_as_float(u << 16); }
__device__ __forceinline__ float b2f_hi(unsigned u) { return __uint_as_float(u & 0xffff0000u); }

__device__ __forceinline__ short f2b(float x) {
    unsigned u = __float_as_uint(x);
    unsigned r = (u + 0x7fffu + ((u >> 16) & 1u)) >> 16;
    return (short)r;
}

// ---------------------------------------------------------------------------
// 0) Pack W into MFMA B-fragment order (bf16) + fused logit matrix V = W·A'
//    (9th n-tile), c = b·A', and init the per-bin arena cursors.
// ---------------------------------------------------------------------------
__global__ __launch_bounds__(256) void pack_kernel(
    const float* __restrict__ W_src, const float* __restrict__ W_dst,
    const float* __restrict__ b_src, const float* __restrict__ b_dst,
    const float* __restrict__ attn,  // [8,32]
    uint4* __restrict__ wp_src, uint4* __restrict__ wp_dst,
    float* __restrict__ c_all,       // [16]
    int* __restrict__ cursor, int nCoarse)
{
    const int e = blockIdx.x * 256 + threadIdx.x;
    if (e < 4608) {
        const int which = e / 2304;
        const int e2 = e % 2304;
        const float* W = which ? W_dst : W_src;
        uint4* wp = which ? wp_dst : wp_src;
        const int aoff = which ? 16 : 0;
        short out[8];
        if (e2 < 2048) {                    // W tiles
            const int t = e2 >> 8, q = (e2 >> 6) & 3, l = e2 & 63;
            const int kbase = (l >> 4) * 8 + q * 32;
            const int n = t * 16 + (l & 15);
            #pragma unroll
            for (int j = 0; j < 8; ++j) out[j] = f2b(W[(size_t)(kbase + j) * 128 + n]);
            *(uint4*)&wp[(t * 4 + q) * 64 + l] = *(uint4*)out;
        } else {                            // V tile (fused logits)
            const int e3 = e2 - 2048;
            const int q = e3 >> 6, l = e3 & 63;
            const int kbase = (l >> 4) * 8 + q * 32;
            const int n = l & 15;
            #pragma unroll
            for (int j = 0; j < 8; ++j) {
                float v = 0.f;
                if (n < 8) {
                    for (int dd = 0; dd < 16; ++dd)
                        v += W[(size_t)(kbase + j) * 128 + n * 16 + dd] * attn[n * 32 + aoff + dd];
                }
                out[j] = f2b(v);
            }
            *(uint4*)&wp[(32 + q) * 64 + l] = *(uint4*)out;
        }
    } else if (e < 4624) {                  // c = b·A'
        const int k = e - 4608;
        const int which = k >> 3, kk = k & 7;
        const float* bb = which ? b_dst : b_src;
        const int aoff = which ? 16 : 0;
        float v = 0.f;
        for (int dd = 0; dd < 16; ++dd) v += bb[kk * 16 + dd] * attn[kk * 32 + aoff + dd];
        c_all[k] = v;
    } else if (e < 4624 + nCoarse) {        // arena cursor init
        const int c = e - 4624;
        cursor[c] = c * CAP;
    }
}

// ---------------------------------------------------------------------------
// scatter body: LDS per-bin count -> one chunk reservation per bin (returning
// atomic) -> scatter packed (s<<5 | d&31) into the bin's arena. Coarse bins
// give ~contiguous write runs (round-4 lesson: exact-dst scatter = 64B
// sector amplification, 112MB writes).
// ---------------------------------------------------------------------------
__device__ __forceinline__ void scatter_body(
    const int* __restrict__ src_idx, const int* __restrict__ dst_idx,
    int* __restrict__ cursor, int* __restrict__ coarse,
    int nEdges, int nCoarse, int bx)
{
    __shared__ int lcnt[MAXC];
    __shared__ int lbase[MAXC];
    const int t = threadIdx.x;
    for (int i = t; i < nCoarse; i += 256) lcnt[i] = 0;
    __syncthreads();
    const int e0 = bx * EPB;
    const int e1 = min(e0 + EPB, nEdges);
    for (int e = e0 + t; e < e1; e += 256) atomicAdd(&lcnt[dst_idx[e] >> 5], 1);
    __syncthreads();
    for (int i = t; i < nCoarse; i += 256) {
        const int c = lcnt[i];
        lbase[i] = c ? atomicAdd(&cursor[i], c) : 0;
        lcnt[i] = 0;                       // reuse as running cursor
    }
    __syncthreads();
    for (int e = e0 + t; e < e1; e += 256) {
        const int d = dst_idx[e];
        const int s = src_idx[e];
        const int bin = d >> 5;
        const int lr = atomicAdd(&lcnt[bin], 1);
        const int pos = lbase[bin] + lr;
        if (pos < (bin + 1) * CAP)         // safety clamp
            coarse[pos] = (s << 5) | (d & 31);
    }
}

// ---------------------------------------------------------------------------
// MFMA projection body: h = feat·W + b (bf16 in, fp32 acc), fused logit via
// 9th n-tile. Wave = 2 m-tiles (32 rows); block = 128 rows.
// Logits are written PRE-SCALED by log2(e): leaky-ReLU is positively
// homogeneous, so exp(leaky(el+er)) == exp2(leaky(el'+er')) downstream ->
// single v_exp_f32 per edge in the reduce.
// ---------------------------------------------------------------------------
template<bool STORE_H>
__device__ __forceinline__ void proj_body(
    const float* __restrict__ feat, const uint4* __restrict__ wp,
    const float* __restrict__ b, const float* __restrict__ cvec,
    short* __restrict__ hs_out, float* __restrict__ el_out,
    int N, int bx)
{
    const int t = threadIdx.x;
    const int lane = t & 63;
    const int w = t >> 6;
    const int m  = lane & 15;
    const int q8 = lane >> 4;
    const int row0 = bx * 128 + w * 32;

    f32x4 acc0[9], acc1[9];
    #pragma unroll
    for (int tt = 0; tt < 8; ++tt) {
        const float bn = b[tt * 16 + m];
        acc0[tt] = (f32x4){bn, bn, bn, bn};
        acc1[tt] = (f32x4){bn, bn, bn, bn};
    }
    acc0[8] = (f32x4){0.f, 0.f, 0.f, 0.f};
    acc1[8] = (f32x4){0.f, 0.f, 0.f, 0.f};

    int rowA0 = row0 + m;      if (rowA0 >= N) rowA0 = N - 1;
    int rowA1 = row0 + 16 + m; if (rowA1 >= N) rowA1 = N - 1;
    const float* f0 = feat + (size_t)rowA0 * 128 + q8 * 8;
    const float* f1 = feat + (size_t)rowA1 * 128 + q8 * 8;
    const bf16x8* wpv = (const bf16x8*)wp;

    #pragma unroll
    for (int kc = 0; kc < 4; ++kc) {
        const float4 fa0 = *(const float4*)(f0 + kc * 32);
        const float4 fb0 = *(const float4*)(f0 + kc * 32 + 4);
        const float4 fa1 = *(const float4*)(f1 + kc * 32);
        const float4 fb1 = *(const float4*)(f1 + kc * 32 + 4);
        bf16x8 a0, a1;
        a0[0]=f2b(fa0.x); a0[1]=f2b(fa0.y); a0[2]=f2b(fa0.z); a0[3]=f2b(fa0.w);
        a0[4]=f2b(fb0.x); a0[5]=f2b(fb0.y); a0[6]=f2b(fb0.z); a0[7]=f2b(fb0.w);
        a1[0]=f2b(fa1.x); a1[1]=f2b(fa1.y); a1[2]=f2b(fa1.z); a1[3]=f2b(fa1.w);
        a1[4]=f2b(fb1.x); a1[5]=f2b(fb1.y); a1[6]=f2b(fb1.z); a1[7]=f2b(fb1.w);
        #pragma unroll
        for (int tt = 0; tt < 8; ++tt) {
            const bf16x8 bf = wpv[(tt * 4 + kc) * 64 + lane];
            acc0[tt] = __builtin_amdgcn_mfma_f32_16x16x32_bf16(a0, bf, acc0[tt], 0, 0, 0);
            acc1[tt] = __builtin_amdgcn_mfma_f32_16x16x32_bf16(a1, bf, acc1[tt], 0, 0, 0);
        }
        {
            const bf16x8 bv = wpv[(32 + kc) * 64 + lane];
            acc0[8] = __builtin_amdgcn_mfma_f32_16x16x32_bf16(a0, bv, acc0[8], 0, 0, 0);
            acc1[8] = __builtin_amdgcn_mfma_f32_16x16x32_bf16(a1, bv, acc1[8], 0, 0, 0);
        }
    }

    #pragma unroll
    for (int half = 0; half < 2; ++half) {
        const f32x4* acc = half ? acc1 : acc0;
        const int rbase = row0 + half * 16 + q8 * 4;
        #pragma unroll
        for (int reg = 0; reg < 4; ++reg) {
            const int row = rbase + reg;
            if (row < N) {
                if (STORE_H) {
                    #pragma unroll
                    for (int tt = 0; tt < 8; ++tt)
                        hs_out[(size_t)row * 128 + tt * 16 + m] = f2b(acc[tt][reg]);
                }
                if (m < 8) el_out[(size_t)row * 8 + m] = (acc[8][reg] + cvec[m]) * LOG2E;
            }
        }
    }
}

// ---------------------------------------------------------------------------
// 1) fused: arena scatter + both MFMA projections (disjoint pipes).
// ---------------------------------------------------------------------------
__global__ __launch_bounds__(256, 2) void fused_kernel(
    const float* __restrict__ feat_src, const float* __restrict__ feat_dst,
    const uint4* __restrict__ wp_src, const uint4* __restrict__ wp_dst,
    const float* __restrict__ b_src, const float* __restrict__ b_dst,
    const float* __restrict__ c_all,
    short* __restrict__ hs, float* __restrict__ el, float* __restrict__ er,
    const int* __restrict__ src_idx, const int* __restrict__ dst_idx,
    int* __restrict__ cursor, int* __restrict__ coarse,
    int n_src, int n_dst, int nEdges, int nCoarse, int nSB, int pSrcBlocks)
{
    int bx = blockIdx.x;
    if (bx < nSB) { scatter_body(src_idx, dst_idx, cursor, coarse, nEdges, nCoarse, bx); return; }
    bx -= nSB;
    if (bx < pSrcBlocks) {
        proj_body<true>(feat_src, wp_src, b_src, c_all, hs, el, n_src, bx);
        return;
    }
    bx -= pSrcBlocks;
    proj_body<false>(feat_dst, wp_dst, b_dst, c_all + 8, nullptr, er, n_dst, bx);
}

// ---------------------------------------------------------------------------
// 2) sort+reduce: one 256-thread block (4 waves) per 32-dst bin, register-
//    staged counting sort (round-6 verified). Reduce phase is now a 2-stage
//    software pipeline: iteration n issues the gathers for pair n+1 (whose
//    fpk index was read at n-1) and the fpk read for n+2, then computes pair
//    n from values loaded one full iteration earlier -- every wait is on a
//    ~1-iteration-old request instead of the serial LDS->global chain that
//    capped round 6 at VALUBusy 49%.
// ---------------------------------------------------------------------------
__global__ __launch_bounds__(256, 8) void sort_reduce_kernel(
    const int* __restrict__ coarse, const int* __restrict__ cursor,
    const float* __restrict__ el,   // [N_src,8] pre-scaled by log2(e)
    const float* __restrict__ er,   // [N_dst,8] pre-scaled by log2(e)
    const unsigned short* __restrict__ hs, // [N_src,128] bf16 bits
    float* __restrict__ out,        // [N_dst,128]
    int n_dst, int nCoarse)
{
    __shared__ int fpk[CAP];        // 8 KB sorted packed edges
    __shared__ int h[BINSZ];        // per-dst degree
    __shared__ int lbeg[BINSZ];     // per-dst local start
    __shared__ int cu[BINSZ];
    __shared__ float erL[BINSZ * 8];
    const int t = threadIdx.x, c = blockIdx.x;
    const int base_in = c * CAP;
    const int cnt = min(cursor[c] - base_in, CAP);

    {                                       // er preload (256 = 32 dst x 8)
        const int d = c * BINSZ + (t >> 3);
        erL[t] = (d < n_dst) ? er[(size_t)d * 8 + (t & 7)] : 0.f;
    }
    if (t < BINSZ) h[t] = 0;
    __syncthreads();

    int ev[8];                              // register-staged bin slice
    #pragma unroll
    for (int r = 0; r < 8; ++r) {
        const int idx = t + (r << 8);
        ev[r] = (idx < cnt) ? coarse[base_in + idx] : -1;
    }
    #pragma unroll
    for (int r = 0; r < 8; ++r)
        if (ev[r] >= 0) atomicAdd(&h[ev[r] & 31], 1);
    __syncthreads();
    if (t < BINSZ) {                        // 32-wide exclusive shfl scan
        const int v = h[t];
        int sc = v;
        #pragma unroll
        for (int off = 1; off < BINSZ; off <<= 1) {
            const int nb = __shfl_up(sc, off);
            if (t >= off) sc += nb;
        }
        lbeg[t] = sc - v;
        cu[t]   = sc - v;
    }
    __syncthreads();
    #pragma unroll
    for (int r = 0; r < 8; ++r)
        if (ev[r] >= 0) {
            const int p = atomicAdd(&cu[ev[r] & 31], 1);
            fpk[p] = ev[r];
        }
    __syncthreads();

    const int w = t >> 6, lane = t & 63;    // w in 0..3
    const int sub = lane >> 5;        // which edge of the pair
    const int l32 = lane & 31;        // channel group 4*l32..4*l32+3
    const int k   = l32 >> 2;         // head
    const uint2* hs2 = (const uint2*)hs;   // 32 uint2 per 128-ch row
    for (int j = 0; j < 8; ++j) {
        const int dl = w * 8 + j;
        const int d  = c * BINSZ + dl;
        if (d >= n_dst) break;        // wave-uniform
        const float erk = erL[dl * 8 + k];
        const int beg = lbeg[dl], end = lbeg[dl] + h[dl];
        float a0 = 0.f, a1 = 0.f, a2 = 0.f, a3 = 0.f, es = 0.f;

        // ---- software-pipelined gather loop (depth 2) ----
        int i  = beg + sub;
        float lA = 0.f; uint2 uA = make_uint2(0u, 0u);
        if (i < end) {
            const int sA = fpk[i] >> 5;
            lA = el[(size_t)sA * 8 + k];
            uA = hs2[(size_t)sA * 32 + l32];
        }
        int i2 = i + 2;
        int sB = (i2 < end) ? (fpk[i2] >> 5) : 0;
        while (i < end) {
            const int i3 = i2 + 2;
            float lB = 0.f; uint2 uB = uA;
            if (i2 < end) {                 // issue next pair's gathers
                lB = el[(size_t)sB * 8 + k];
                uB = hs2[(size_t)sB * 32 + l32];
            }
            const int sC = (i3 < end) ? (fpk[i3] >> 5) : 0;  // LDS prefetch
            // compute current pair (loaded one iteration ago)
            float x = lA + erk; x = (x >= 0.f) ? x : NEG_SLOPE * x;
            const float ee = EXP2F(x);
            es += ee;
            a0 = fmaf(ee, b2f_lo(uA.x), a0); a1 = fmaf(ee, b2f_hi(uA.x), a1);
            a2 = fmaf(ee, b2f_lo(uA.y), a2); a3 = fmaf(ee, b2f_hi(uA.y), a3);
            // rotate pipeline
            i = i2; i2 = i3; sB = sC; lA = lB; uA = uB;
        }

        es += __shfl_xor(es, 32);
        a0 += __shfl_xor(a0, 32);
        a1 += __shfl_xor(a1, 32);
        a2 += __shfl_xor(a2, 32);
        a3 += __shfl_xor(a3, 32);
        if (sub == 0) {
            const float inv = (es > 0.f) ? 1.f / es : 0.f;
            float4 o;
            o.x = a0 * inv; o.y = a1 * inv; o.z = a2 * inv; o.w = a3 * inv;
            *(float4*)(out + (size_t)d * 128 + l32 * 4) = o;
        }
    }
}

extern "C" void kernel_launch(void* const* d_in, const int* in_sizes, int n_in,
                              void* d_out, int out_size, void* d_ws, size_t ws_size,
                              hipStream_t stream) {
    const float* feat_src = (const float*)d_in[0];
    const float* feat_dst = (const float*)d_in[1];
    const float* W_src    = (const float*)d_in[2];
    const float* b_src    = (const float*)d_in[3];
    const float* W_dst    = (const float*)d_in[4];
    const float* b_dst    = (const float*)d_in[5];
    const float* attn     = (const float*)d_in[6];
    const int*   src_idx  = (const int*)d_in[7];
    const int*   dst_idx  = (const int*)d_in[8];
    float* out = (float*)d_out;

    const int n_src  = in_sizes[0] / 128;
    const int n_dst  = in_sizes[1] / 128;
    const int nEdges = in_sizes[7];

    const int nCoarse = (n_dst + BINSZ - 1) / BINSZ;       // 1563
    const int nSB     = (nEdges + EPB - 1) / EPB;          // 196
    const int pSrc    = (n_src + 127) / 128;
    const int pDst    = (n_dst + 127) / 128;

    // workspace layout
    unsigned short* hs = (unsigned short*)d_ws;            // n_src*128 bf16 (12.8 MB)
    float* el = (float*)(hs + (size_t)n_src * 128);        // n_src*8
    float* er = el + (size_t)n_src * 8;                    // n_dst*8
    int* cursor = (int*)(er + (size_t)n_dst * 8);          // nCoarse
    uintptr_t p = (uintptr_t)(cursor + nCoarse);
    p = (p + 15) & ~(uintptr_t)15;
    int* coarse = (int*)p;                                 // nCoarse*CAP (12.8 MB)
    uintptr_t p2 = (uintptr_t)(coarse + (size_t)nCoarse * CAP);
    p2 = (p2 + 15) & ~(uintptr_t)15;
    uint4* wp_src = (uint4*)p2;                            // 36*64 uint4
    uint4* wp_dst = wp_src + 36 * 64;                      // 36*64 uint4
    float* c_all  = (float*)(wp_dst + 36 * 64);            // 16 floats

    const int packBlocks = (4624 + nCoarse + 255) / 256;
    pack_kernel<<<packBlocks, 256, 0, stream>>>(W_src, W_dst, b_src, b_dst, attn,
                                                wp_src, wp_dst, c_all, cursor, nCoarse);

    fused_kernel<<<nSB + pSrc + pDst, 256, 0, stream>>>(
        feat_src, feat_dst, wp_src, wp_dst, b_src, b_dst, c_all,
        (short*)hs, el, er, src_idx, dst_idx, cursor, coarse,
        n_src, n_dst, nEdges, nCoarse, nSB, pSrc);

    sort_reduce_kernel<<<nCoarse, 256, 0, stream>>>(coarse, cursor, el, er,
                                                    hs, out, n_dst, nCoarse);
}

// Round 9
// 218.243 us; speedup vs baseline: 1.0672x; 1.0672x over previous
//
#include <hip/hip_runtime.h>
#include <hip/hip_bf16.h>

#define NEG_SLOPE 0.2f
#define LOG2E 1.4426950408889634f
#define EPB   8192   // edges per scatter block (round-0 verified; 4096 regressed)
#define BINSZ 32     // dsts per bin (256-thread blocks -> 8 blocks/CU residency)
#define CAP   2048   // arena slots per 32-dst bin (mean 1024, sigma 32 -> 32 sigma)
#define MAXC  2048   // max bins; ceil(50000/32) = 1563

#if defined(__has_builtin) && __has_builtin(__builtin_amdgcn_exp2f)
#define EXP2F(x) __builtin_amdgcn_exp2f(x)
#else
#define EXP2F(x) exp2f(x)
#endif

typedef __attribute__((ext_vector_type(8))) short bf16x8;
typedef __attribute__((ext_vector_type(4))) float f32x4;

__device__ __forceinline__ float b2f_lo(unsigned u) { return __uint_as_float(u << 16); }
__device__ __forceinline__ float b2f_hi(unsigned u) { return __uint_as_float(u & 0xffff0000u); }

__device__ __forceinline__ short f2b(float x) {
    unsigned u = __float_as_uint(x);
    unsigned r = (u + 0x7fffu + ((u >> 16) & 1u)) >> 16;
    return (short)r;
}

// ---------------------------------------------------------------------------
// 0) Pack W into MFMA B-fragment order (bf16) + fused logit matrix V = W·A'
//    (9th n-tile), c = b·A', and init the per-bin arena cursors.
// ---------------------------------------------------------------------------
__global__ __launch_bounds__(256) void pack_kernel(
    const float* __restrict__ W_src, const float* __restrict__ W_dst,
    const float* __restrict__ b_src, const float* __restrict__ b_dst,
    const float* __restrict__ attn,  // [8,32]
    uint4* __restrict__ wp_src, uint4* __restrict__ wp_dst,
    float* __restrict__ c_all,       // [16]
    int* __restrict__ cursor, int nCoarse)
{
    const int e = blockIdx.x * 256 + threadIdx.x;
    if (e < 4608) {
        const int which = e / 2304;
        const int e2 = e % 2304;
        const float* W = which ? W_dst : W_src;
        uint4* wp = which ? wp_dst : wp_src;
        const int aoff = which ? 16 : 0;
        short out[8];
        if (e2 < 2048) {                    // W tiles
            const int t = e2 >> 8, q = (e2 >> 6) & 3, l = e2 & 63;
            const int kbase = (l >> 4) * 8 + q * 32;
            const int n = t * 16 + (l & 15);
            #pragma unroll
            for (int j = 0; j < 8; ++j) out[j] = f2b(W[(size_t)(kbase + j) * 128 + n]);
            *(uint4*)&wp[(t * 4 + q) * 64 + l] = *(uint4*)out;
        } else {                            // V tile (fused logits)
            const int e3 = e2 - 2048;
            const int q = e3 >> 6, l = e3 & 63;
            const int kbase = (l >> 4) * 8 + q * 32;
            const int n = l & 15;
            #pragma unroll
            for (int j = 0; j < 8; ++j) {
                float v = 0.f;
                if (n < 8) {
                    for (int dd = 0; dd < 16; ++dd)
                        v += W[(size_t)(kbase + j) * 128 + n * 16 + dd] * attn[n * 32 + aoff + dd];
                }
                out[j] = f2b(v);
            }
            *(uint4*)&wp[(32 + q) * 64 + l] = *(uint4*)out;
        }
    } else if (e < 4624) {                  // c = b·A'
        const int k = e - 4608;
        const int which = k >> 3, kk = k & 7;
        const float* bb = which ? b_dst : b_src;
        const int aoff = which ? 16 : 0;
        float v = 0.f;
        for (int dd = 0; dd < 16; ++dd) v += bb[kk * 16 + dd] * attn[kk * 32 + aoff + dd];
        c_all[k] = v;
    } else if (e < 4624 + nCoarse) {        // arena cursor init
        const int c = e - 4624;
        cursor[c] = c * CAP;
    }
}

// ---------------------------------------------------------------------------
// scatter body: LDS per-bin count -> one chunk reservation per bin (returning
// atomic) -> scatter packed (s<<5 | d&31) into the bin's arena. Coarse bins
// give ~contiguous write runs (round-4 lesson: exact-dst scatter = 64B
// sector amplification, 112MB writes).
// ---------------------------------------------------------------------------
__device__ __forceinline__ void scatter_body(
    const int* __restrict__ src_idx, const int* __restrict__ dst_idx,
    int* __restrict__ cursor, int* __restrict__ coarse,
    int nEdges, int nCoarse, int bx)
{
    __shared__ int lcnt[MAXC];
    __shared__ int lbase[MAXC];
    const int t = threadIdx.x;
    for (int i = t; i < nCoarse; i += 256) lcnt[i] = 0;
    __syncthreads();
    const int e0 = bx * EPB;
    const int e1 = min(e0 + EPB, nEdges);
    for (int e = e0 + t; e < e1; e += 256) atomicAdd(&lcnt[dst_idx[e] >> 5], 1);
    __syncthreads();
    for (int i = t; i < nCoarse; i += 256) {
        const int c = lcnt[i];
        lbase[i] = c ? atomicAdd(&cursor[i], c) : 0;
        lcnt[i] = 0;                       // reuse as running cursor
    }
    __syncthreads();
    for (int e = e0 + t; e < e1; e += 256) {
        const int d = dst_idx[e];
        const int s = src_idx[e];
        const int bin = d >> 5;
        const int lr = atomicAdd(&lcnt[bin], 1);
        const int pos = lbase[bin] + lr;
        if (pos < (bin + 1) * CAP)         // safety clamp
            coarse[pos] = (s << 5) | (d & 31);
    }
}

// ---------------------------------------------------------------------------
// MFMA projection body: h = feat·W + b (bf16 in, fp32 acc), fused logit via
// 9th n-tile. Wave = 2 m-tiles (32 rows); block = 128 rows.
// Logits are written PRE-SCALED by log2(e): leaky-ReLU is positively
// homogeneous, so exp(leaky(el+er)) == exp2(leaky(el'+er')) downstream ->
// single v_exp_f32 per edge in the reduce.
// ---------------------------------------------------------------------------
template<bool STORE_H>
__device__ __forceinline__ void proj_body(
    const float* __restrict__ feat, const uint4* __restrict__ wp,
    const float* __restrict__ b, const float* __restrict__ cvec,
    short* __restrict__ hs_out, float* __restrict__ el_out,
    int N, int bx)
{
    const int t = threadIdx.x;
    const int lane = t & 63;
    const int w = t >> 6;
    const int m  = lane & 15;
    const int q8 = lane >> 4;
    const int row0 = bx * 128 + w * 32;

    f32x4 acc0[9], acc1[9];
    #pragma unroll
    for (int tt = 0; tt < 8; ++tt) {
        const float bn = b[tt * 16 + m];
        acc0[tt] = (f32x4){bn, bn, bn, bn};
        acc1[tt] = (f32x4){bn, bn, bn, bn};
    }
    acc0[8] = (f32x4){0.f, 0.f, 0.f, 0.f};
    acc1[8] = (f32x4){0.f, 0.f, 0.f, 0.f};

    int rowA0 = row0 + m;      if (rowA0 >= N) rowA0 = N - 1;
    int rowA1 = row0 + 16 + m; if (rowA1 >= N) rowA1 = N - 1;
    const float* f0 = feat + (size_t)rowA0 * 128 + q8 * 8;
    const float* f1 = feat + (size_t)rowA1 * 128 + q8 * 8;
    const bf16x8* wpv = (const bf16x8*)wp;

    #pragma unroll
    for (int kc = 0; kc < 4; ++kc) {
        const float4 fa0 = *(const float4*)(f0 + kc * 32);
        const float4 fb0 = *(const float4*)(f0 + kc * 32 + 4);
        const float4 fa1 = *(const float4*)(f1 + kc * 32);
        const float4 fb1 = *(const float4*)(f1 + kc * 32 + 4);
        bf16x8 a0, a1;
        a0[0]=f2b(fa0.x); a0[1]=f2b(fa0.y); a0[2]=f2b(fa0.z); a0[3]=f2b(fa0.w);
        a0[4]=f2b(fb0.x); a0[5]=f2b(fb0.y); a0[6]=f2b(fb0.z); a0[7]=f2b(fb0.w);
        a1[0]=f2b(fa1.x); a1[1]=f2b(fa1.y); a1[2]=f2b(fa1.z); a1[3]=f2b(fa1.w);
        a1[4]=f2b(fb1.x); a1[5]=f2b(fb1.y); a1[6]=f2b(fb1.z); a1[7]=f2b(fb1.w);
        #pragma unroll
        for (int tt = 0; tt < 8; ++tt) {
            const bf16x8 bf = wpv[(tt * 4 + kc) * 64 + lane];
            acc0[tt] = __builtin_amdgcn_mfma_f32_16x16x32_bf16(a0, bf, acc0[tt], 0, 0, 0);
            acc1[tt] = __builtin_amdgcn_mfma_f32_16x16x32_bf16(a1, bf, acc1[tt], 0, 0, 0);
        }
        {
            const bf16x8 bv = wpv[(32 + kc) * 64 + lane];
            acc0[8] = __builtin_amdgcn_mfma_f32_16x16x32_bf16(a0, bv, acc0[8], 0, 0, 0);
            acc1[8] = __builtin_amdgcn_mfma_f32_16x16x32_bf16(a1, bv, acc1[8], 0, 0, 0);
        }
    }

    #pragma unroll
    for (int half = 0; half < 2; ++half) {
        const f32x4* acc = half ? acc1 : acc0;
        const int rbase = row0 + half * 16 + q8 * 4;
        #pragma unroll
        for (int reg = 0; reg < 4; ++reg) {
            const int row = rbase + reg;
            if (row < N) {
                if (STORE_H) {
                    #pragma unroll
                    for (int tt = 0; tt < 8; ++tt)
                        hs_out[(size_t)row * 128 + tt * 16 + m] = f2b(acc[tt][reg]);
                }
                if (m < 8) el_out[(size_t)row * 8 + m] = (acc[8][reg] + cvec[m]) * LOG2E;
            }
        }
    }
}

// ---------------------------------------------------------------------------
// 1) fused: arena scatter + both MFMA projections (disjoint pipes).
// ---------------------------------------------------------------------------
__global__ __launch_bounds__(256, 2) void fused_kernel(
    const float* __restrict__ feat_src, const float* __restrict__ feat_dst,
    const uint4* __restrict__ wp_src, const uint4* __restrict__ wp_dst,
    const float* __restrict__ b_src, const float* __restrict__ b_dst,
    const float* __restrict__ c_all,
    short* __restrict__ hs, float* __restrict__ el, float* __restrict__ er,
    const int* __restrict__ src_idx, const int* __restrict__ dst_idx,
    int* __restrict__ cursor, int* __restrict__ coarse,
    int n_src, int n_dst, int nEdges, int nCoarse, int nSB, int pSrcBlocks)
{
    int bx = blockIdx.x;
    if (bx < nSB) { scatter_body(src_idx, dst_idx, cursor, coarse, nEdges, nCoarse, bx); return; }
    bx -= nSB;
    if (bx < pSrcBlocks) {
        proj_body<true>(feat_src, wp_src, b_src, c_all, hs, el, n_src, bx);
        return;
    }
    bx -= pSrcBlocks;
    proj_body<false>(feat_dst, wp_dst, b_dst, c_all + 8, nullptr, er, n_dst, bx);
}

// ---------------------------------------------------------------------------
// 2) sort+reduce: one 256-thread block (4 waves) per 32-dst bin, register-
//    staged counting sort (round-6 verified). Reduce phase: 2-pair PING-PONG
//    pipeline -- consume pair A (loaded one iteration ago), refill A for i+4,
//    consume pair B, refill B for i+6. No register rotation (round-8 lesson:
//    rotation movs force vmcnt(0) in the same iteration and the compiler
//    collapses the pipeline); loads land directly in their consumption
//    registers so the compiler emits counted vmcnt waits on iteration-old
//    requests.
// ---------------------------------------------------------------------------
__global__ __launch_bounds__(256, 8) void sort_reduce_kernel(
    const int* __restrict__ coarse, const int* __restrict__ cursor,
    const float* __restrict__ el,   // [N_src,8] pre-scaled by log2(e)
    const float* __restrict__ er,   // [N_dst,8] pre-scaled by log2(e)
    const unsigned short* __restrict__ hs, // [N_src,128] bf16 bits
    float* __restrict__ out,        // [N_dst,128]
    int n_dst, int nCoarse)
{
    __shared__ int fpk[CAP];        // 8 KB sorted packed edges
    __shared__ int h[BINSZ];        // per-dst degree
    __shared__ int lbeg[BINSZ];     // per-dst local start
    __shared__ int cu[BINSZ];
    __shared__ float erL[BINSZ * 8];
    const int t = threadIdx.x, c = blockIdx.x;
    const int base_in = c * CAP;
    const int cnt = min(cursor[c] - base_in, CAP);

    {                                       // er preload (256 = 32 dst x 8)
        const int d = c * BINSZ + (t >> 3);
        erL[t] = (d < n_dst) ? er[(size_t)d * 8 + (t & 7)] : 0.f;
    }
    if (t < BINSZ) h[t] = 0;
    __syncthreads();

    int ev[8];                              // register-staged bin slice
    #pragma unroll
    for (int r = 0; r < 8; ++r) {
        const int idx = t + (r << 8);
        ev[r] = (idx < cnt) ? coarse[base_in + idx] : -1;
    }
    #pragma unroll
    for (int r = 0; r < 8; ++r)
        if (ev[r] >= 0) atomicAdd(&h[ev[r] & 31], 1);
    __syncthreads();
    if (t < BINSZ) {                        // 32-wide exclusive shfl scan
        const int v = h[t];
        int sc = v;
        #pragma unroll
        for (int off = 1; off < BINSZ; off <<= 1) {
            const int nb = __shfl_up(sc, off);
            if (t >= off) sc += nb;
        }
        lbeg[t] = sc - v;
        cu[t]   = sc - v;
    }
    __syncthreads();
    #pragma unroll
    for (int r = 0; r < 8; ++r)
        if (ev[r] >= 0) {
            const int p = atomicAdd(&cu[ev[r] & 31], 1);
            fpk[p] = ev[r];
        }
    __syncthreads();

    const int w = t >> 6, lane = t & 63;    // w in 0..3
    const int sub = lane >> 5;        // which edge of the pair
    const int l32 = lane & 31;        // channel group 4*l32..4*l32+3
    const int k   = l32 >> 2;         // head
    const uint2* hs2 = (const uint2*)hs;   // 32 uint2 per 128-ch row
    for (int j = 0; j < 8; ++j) {
        const int dl = w * 8 + j;
        const int d  = c * BINSZ + dl;
        if (d >= n_dst) break;        // wave-uniform
        const float erk = erL[dl * 8 + k];
        const int beg = lbeg[dl], end = lbeg[dl] + h[dl];
        float a0 = 0.f, a1 = 0.f, a2 = 0.f, a3 = 0.f, es = 0.f;

        // ---- ping-pong pipelined gather loop ----
        int iA = beg + sub;
        int iB = iA + 2;
        float lA = 0.f, lB = 0.f;
        uint2 uA = make_uint2(0u, 0u), uB = make_uint2(0u, 0u);
        if (iA < end) {
            const int s = fpk[iA] >> 5;
            lA = el[(size_t)s * 8 + k];
            uA = hs2[(size_t)s * 32 + l32];
        }
        if (iB < end) {
            const int s = fpk[iB] >> 5;
            lB = el[(size_t)s * 8 + k];
            uB = hs2[(size_t)s * 32 + l32];
        }
        while (iA < end) {
            // consume A (loads issued one iteration ago)
            {
                float x = lA + erk; x = (x >= 0.f) ? x : NEG_SLOPE * x;
                const float ee = EXP2F(x);
                es += ee;
                a0 = fmaf(ee, b2f_lo(uA.x), a0); a1 = fmaf(ee, b2f_hi(uA.x), a1);
                a2 = fmaf(ee, b2f_lo(uA.y), a2); a3 = fmaf(ee, b2f_hi(uA.y), a3);
            }
            // refill A for iA+4 (stays outstanding across B's compute)
            const int iA2 = iA + 4;
            if (iA2 < end) {
                const int s = fpk[iA2] >> 5;
                lA = el[(size_t)s * 8 + k];
                uA = hs2[(size_t)s * 32 + l32];
            }
            if (iB < end) {
                // consume B
                float x = lB + erk; x = (x >= 0.f) ? x : NEG_SLOPE * x;
                const float ee = EXP2F(x);
                es += ee;
                a0 = fmaf(ee, b2f_lo(uB.x), a0); a1 = fmaf(ee, b2f_hi(uB.x), a1);
                a2 = fmaf(ee, b2f_lo(uB.y), a2); a3 = fmaf(ee, b2f_hi(uB.y), a3);
                // refill B for iB+4
                const int iB2 = iB + 4;
                if (iB2 < end) {
                    const int s = fpk[iB2] >> 5;
                    lB = el[(size_t)s * 8 + k];
                    uB = hs2[(size_t)s * 32 + l32];
                }
            }
            iA = iA2; iB += 4;
        }

        es += __shfl_xor(es, 32);
        a0 += __shfl_xor(a0, 32);
        a1 += __shfl_xor(a1, 32);
        a2 += __shfl_xor(a2, 32);
        a3 += __shfl_xor(a3, 32);
        if (sub == 0) {
            const float inv = (es > 0.f) ? 1.f / es : 0.f;
            float4 o;
            o.x = a0 * inv; o.y = a1 * inv; o.z = a2 * inv; o.w = a3 * inv;
            *(float4*)(out + (size_t)d * 128 + l32 * 4) = o;
        }
    }
}

extern "C" void kernel_launch(void* const* d_in, const int* in_sizes, int n_in,
                              void* d_out, int out_size, void* d_ws, size_t ws_size,
                              hipStream_t stream) {
    const float* feat_src = (const float*)d_in[0];
    const float* feat_dst = (const float*)d_in[1];
    const float* W_src    = (const float*)d_in[2];
    const float* b_src    = (const float*)d_in[3];
    const float* W_dst    = (const float*)d_in[4];
    const float* b_dst    = (const float*)d_in[5];
    const float* attn     = (const float*)d_in[6];
    const int*   src_idx  = (const int*)d_in[7];
    const int*   dst_idx  = (const int*)d_in[8];
    float* out = (float*)d_out;

    const int n_src  = in_sizes[0] / 128;
    const int n_dst  = in_sizes[1] / 128;
    const int nEdges = in_sizes[7];

    const int nCoarse = (n_dst + BINSZ - 1) / BINSZ;       // 1563
    const int nSB     = (nEdges + EPB - 1) / EPB;          // 196
    const int pSrc    = (n_src + 127) / 128;
    const int pDst    = (n_dst + 127) / 128;

    // workspace layout
    unsigned short* hs = (unsigned short*)d_ws;            // n_src*128 bf16 (12.8 MB)
    float* el = (float*)(hs + (size_t)n_src * 128);        // n_src*8
    float* er = el + (size_t)n_src * 8;                    // n_dst*8
    int* cursor = (int*)(er + (size_t)n_dst * 8);          // nCoarse
    uintptr_t p = (uintptr_t)(cursor + nCoarse);
    p = (p + 15) & ~(uintptr_t)15;
    int* coarse = (int*)p;                                 // nCoarse*CAP (12.8 MB)
    uintptr_t p2 = (uintptr_t)(coarse + (size_t)nCoarse * CAP);
    p2 = (p2 + 15) & ~(uintptr_t)15;
    uint4* wp_src = (uint4*)p2;                            // 36*64 uint4
    uint4* wp_dst = wp_src + 36 * 64;                      // 36*64 uint4
    float* c_all  = (float*)(wp_dst + 36 * 64);            // 16 floats

    const int packBlocks = (4624 + nCoarse + 255) / 256;
    pack_kernel<<<packBlocks, 256, 0, stream>>>(W_src, W_dst, b_src, b_dst, attn,
                                                wp_src, wp_dst, c_all, cursor, nCoarse);

    fused_kernel<<<nSB + pSrc + pDst, 256, 0, stream>>>(
        feat_src, feat_dst, wp_src, wp_dst, b_src, b_dst, c_all,
        (short*)hs, el, er, src_idx, dst_idx, cursor, coarse,
        n_src, n_dst, nEdges, nCoarse, nSB, pSrc);

    sort_reduce_kernel<<<nCoarse, 256, 0, stream>>>(coarse, cursor, el, er,
                                                    hs, out, n_dst, nCoarse);
}